// Round 5
// baseline (264.936 us; speedup 1.0000x reference)
//
#include <hip/hip_runtime.h>
#include <math.h>

#define HEADS 4
#define NEG 0.2f

typedef __attribute__((ext_vector_type(8))) short bf16x8;
typedef __attribute__((ext_vector_type(4))) float f32x4;
typedef unsigned int u32;

__device__ inline float bf2f(unsigned short u) {
    union { unsigned int i; float f; } v; v.i = ((unsigned int)u) << 16; return v.f;
}
__device__ inline unsigned short f2bf(float f) {
    union { float f; unsigned int i; } v; v.f = f;
    unsigned int r = v.i + 0x7FFF + ((v.i >> 16) & 1);
    return (unsigned short)(r >> 16);
}
// async global->LDS, 16B/lane; LDS dest = wave-uniform base + lane*16
__device__ inline void load_lds16(const unsigned short* g, unsigned short* l) {
    __builtin_amdgcn_global_load_lds((const __attribute__((address_space(1))) u32*)g,
                                     (__attribute__((address_space(3))) u32*)l, 16, 0, 0);
}

// ============ GEMM1 (split-bf16, 128x128 tile) + fused scores1 ============
// A: [M,512] bf16 [Ah|Al]; Bt: [256,768] rows [Wh;Wh;Wl]
// C: HEAD-MAJOR [4][M][64] bf16   es/ed: HEAD-MAJOR [4][M] fp32
__global__ __launch_bounds__(256) void gemm1_scores(const unsigned short* __restrict__ A,
                                                    const unsigned short* __restrict__ Bt,
                                                    unsigned short* __restrict__ C,
                                                    const float* __restrict__ a1s,
                                                    const float* __restrict__ a1d,
                                                    float* __restrict__ es,
                                                    float* __restrict__ ed, int M) {
    __shared__ unsigned short As[128 * 32];
    __shared__ unsigned short Bs[128 * 32];
    const int tid = threadIdx.x;
    const int bm = blockIdx.y * 128, bn = blockIdx.x * 128;
    const int wave = tid >> 6, lane = tid & 63;
    const int wm = (wave >> 1) * 64, wn = (wave & 1) * 64;
    const int lm = lane & 15, kq = lane >> 4;
    const int rA = lane >> 2, cA = (lane & 3) * 8;

    f32x4 acc[4][4] = {};
    for (int k0 = 0; k0 < 768; k0 += 32) {
        const int ka = (k0 < 512) ? k0 : k0 - 512;
#pragma unroll
        for (int i = 0; i < 2; ++i) {
            int c = wave * 2 + i;
            int gr = bm + c * 16 + rA;
            if (gr >= M) gr = M - 1;  // clamp: values discarded at store
            load_lds16(A + (size_t)gr * 512 + ka + cA, &As[c * 16 * 32]);
        }
#pragma unroll
        for (int i = 0; i < 2; ++i) {
            int c = wave * 2 + i;
            load_lds16(Bt + (size_t)(bn + c * 16 + rA) * 768 + k0 + cA, &Bs[c * 16 * 32]);
        }
        __syncthreads();
        bf16x8 af[4], bfr[4];
#pragma unroll
        for (int f = 0; f < 4; ++f) af[f] = *(const bf16x8*)(&As[(wm + f * 16 + lm) * 32 + kq * 8]);
#pragma unroll
        for (int f = 0; f < 4; ++f) bfr[f] = *(const bf16x8*)(&Bs[(wn + f * 16 + lm) * 32 + kq * 8]);
#pragma unroll
        for (int fr = 0; fr < 4; ++fr)
#pragma unroll
            for (int fc = 0; fc < 4; ++fc)
                acc[fr][fc] = __builtin_amdgcn_mfma_f32_16x16x32_bf16(af[fr], bfr[fc], acc[fr][fc], 0, 0, 0);
        __syncthreads();
    }
    // epilogue: each wave owns 64 cols = exactly one head
    const int head = (bn + wn) >> 6;
    float asv[4], adv[4];
#pragma unroll
    for (int fc = 0; fc < 4; ++fc) {
        int ch = fc * 16 + lm;
        asv[fc] = a1s[head * 64 + ch];
        adv[fc] = a1d[head * 64 + ch];
    }
    unsigned short* Ch = C + (size_t)head * M * 64;
#pragma unroll
    for (int fr = 0; fr < 4; ++fr)
#pragma unroll
        for (int i = 0; i < 4; ++i) {
            int row = bm + wm + fr * 16 + kq * 4 + i;
            float se = 0.f, de = 0.f;
#pragma unroll
            for (int fc = 0; fc < 4; ++fc) {
                float c = acc[fr][fc][i];
                se = fmaf(asv[fc], c, se);
                de = fmaf(adv[fc], c, de);
            }
#pragma unroll
            for (int off = 1; off < 16; off <<= 1) {
                se += __shfl_xor(se, off, 64);
                de += __shfl_xor(de, off, 64);
            }
            if (row < M) {
                if (lm == 0) { es[head * M + row] = se; ed[head * M + row] = de; }
#pragma unroll
                for (int fc = 0; fc < 4; ++fc)
                    Ch[(size_t)row * 64 + fc * 16 + lm] = f2bf(acc[fr][fc][i]);
            }
        }
}

// ============ GEMM2 (128x64 tile) + fused scores2 ============
__global__ __launch_bounds__(256) void gemm2_scores(const unsigned short* __restrict__ A,
                                                    const unsigned short* __restrict__ Bt,
                                                    unsigned short* __restrict__ C,
                                                    const float* __restrict__ a2s,
                                                    const float* __restrict__ a2d,
                                                    float* __restrict__ es,
                                                    float* __restrict__ ed, int M) {
    __shared__ unsigned short As[128 * 32];
    __shared__ unsigned short Bs[64 * 32];
    const int tid = threadIdx.x;
    const int bm = blockIdx.y * 128;
    const int wave = tid >> 6, lane = tid & 63;
    const int wm = wave * 32;
    const int lm = lane & 15, kq = lane >> 4;
    const int rA = lane >> 2, cA = (lane & 3) * 8;

    f32x4 acc[2][4] = {};
    for (int k0 = 0; k0 < 768; k0 += 32) {
        const int ka = (k0 < 512) ? k0 : k0 - 512;
#pragma unroll
        for (int i = 0; i < 2; ++i) {
            int c = wave * 2 + i;
            int gr = bm + c * 16 + rA;
            if (gr >= M) gr = M - 1;
            load_lds16(A + (size_t)gr * 512 + ka + cA, &As[c * 16 * 32]);
        }
        {
            int c = wave;
            load_lds16(Bt + (size_t)(c * 16 + rA) * 768 + k0 + cA, &Bs[c * 16 * 32]);
        }
        __syncthreads();
        bf16x8 af[2], bfr[4];
#pragma unroll
        for (int f = 0; f < 2; ++f) af[f] = *(const bf16x8*)(&As[(wm + f * 16 + lm) * 32 + kq * 8]);
#pragma unroll
        for (int f = 0; f < 4; ++f) bfr[f] = *(const bf16x8*)(&Bs[(f * 16 + lm) * 32 + kq * 8]);
#pragma unroll
        for (int fr = 0; fr < 2; ++fr)
#pragma unroll
            for (int fc = 0; fc < 4; ++fc)
                acc[fr][fc] = __builtin_amdgcn_mfma_f32_16x16x32_bf16(af[fr], bfr[fc], acc[fr][fc], 0, 0, 0);
        __syncthreads();
    }
    float asv[4], adv[4];
#pragma unroll
    for (int fc = 0; fc < 4; ++fc) {
        int ch = fc * 16 + lm;
        asv[fc] = a2s[ch];
        adv[fc] = a2d[ch];
    }
#pragma unroll
    for (int fr = 0; fr < 2; ++fr)
#pragma unroll
        for (int i = 0; i < 4; ++i) {
            int row = bm + wm + fr * 16 + kq * 4 + i;
            float se = 0.f, de = 0.f;
#pragma unroll
            for (int fc = 0; fc < 4; ++fc) {
                float c = acc[fr][fc][i];
                se = fmaf(asv[fc], c, se);
                de = fmaf(adv[fc], c, de);
            }
#pragma unroll
            for (int off = 1; off < 16; off <<= 1) {
                se += __shfl_xor(se, off, 64);
                de += __shfl_xor(de, off, 64);
            }
            if (row < M) {
                if (lm == 0) { es[row] = se; ed[row] = de; }
#pragma unroll
                for (int fc = 0; fc < 4; ++fc)
                    C[(size_t)row * 64 + fc * 16 + lm] = f2bf(acc[fr][fc][i]);
            }
        }
}

// ============ fused pre-pass: conv_x + conv_w(1&2) + zero(deg) ============
__global__ __launch_bounds__(256) void pre(const float* __restrict__ x,
                                           const float* __restrict__ W1,
                                           const float* __restrict__ W2,
                                           unsigned short* __restrict__ xs,
                                           unsigned short* __restrict__ Wt1,
                                           unsigned short* __restrict__ Wt2,
                                           int* __restrict__ deg,
                                           int xb, int wb, int N) {
    int b = blockIdx.x, tid = threadIdx.x;
    if (b < xb) {
        int i = b * 256 + tid;
        if (i >= N * 64) return;
        int e0 = i * 4;
        int node = e0 >> 8, c = e0 & 255;
        float4 f = *(const float4*)(x + e0);
        unsigned short h0 = f2bf(f.x), h1 = f2bf(f.y), h2 = f2bf(f.z), h3 = f2bf(f.w);
        uint2 hi, lo;
        hi.x = (u32)h0 | ((u32)h1 << 16);
        hi.y = (u32)h2 | ((u32)h3 << 16);
        lo.x = (u32)f2bf(f.x - bf2f(h0)) | ((u32)f2bf(f.y - bf2f(h1)) << 16);
        lo.y = (u32)f2bf(f.z - bf2f(h2)) | ((u32)f2bf(f.w - bf2f(h3)) << 16);
        *(uint2*)(xs + (size_t)node * 512 + c) = hi;
        *(uint2*)(xs + (size_t)node * 512 + 256 + c) = lo;
    } else if (b < xb + wb) {
        int i = (b - xb) * 256 + tid;
        const float* W;
        unsigned short* Wt;
        int outc;
        if (i < 256 * 768) { W = W1; Wt = Wt1; outc = 256; }
        else {
            i -= 256 * 768;
            if (i >= 64 * 768) return;
            W = W2; Wt = Wt2; outc = 64;
        }
        int n = i / 768, k = i % 768;
        int ksrc = (k < 256) ? k : (k < 512 ? k - 256 : k - 512);
        float f = W[(size_t)ksrc * outc + n];
        unsigned short h = f2bf(f);
        if (k >= 512) h = f2bf(f - bf2f(h));
        Wt[i] = h;
    } else {
        int i = (b - xb - wb) * 256 + tid;
        if (i < N) deg[i] = 0;
    }
}

// ============ CSR build ============
__global__ __launch_bounds__(256) void build_deg(const int* __restrict__ ei, int E, int Np,
                                                 int* __restrict__ deg) {
    int e = blockIdx.x * 256 + threadIdx.x;
    if (e >= E + Np) return;
    int d = (e < E) ? ei[E + e] : (e - E);
    atomicAdd(&deg[d], 1);
}

__global__ __launch_bounds__(1024) void scan_deg(const int* __restrict__ deg,
                                                 int* __restrict__ offs,
                                                 int* __restrict__ cursor, int n) {
    __shared__ int sums[1024];
    int t = threadIdx.x;
    int CH = (n + 1023) >> 10;
    int b = t * CH, e = min(b + CH, n);
    if (b > n) b = n;
    int s = 0;
    for (int i = b; i < e; ++i) s += deg[i];
    int val = s;
    sums[t] = val;
    __syncthreads();
    for (int off = 1; off < 1024; off <<= 1) {
        int o = (t >= off) ? sums[t - off] : 0;
        __syncthreads();
        val += o;
        sums[t] = val;
        __syncthreads();
    }
    int run = val - s;
    for (int i = b; i < e; ++i) {
        offs[i] = run;
        cursor[i] = run;
        run += deg[i];
    }
    if (t == 1023) offs[n] = val;
}

__global__ __launch_bounds__(256) void fill_csr(const int* __restrict__ ei, int E, int Np,
                                                int* __restrict__ cursor, int* __restrict__ csr) {
    int e = blockIdx.x * 256 + threadIdx.x;
    if (e >= E + Np) return;
    int s, d;
    if (e < E) { s = ei[e]; d = ei[E + e]; }
    else       { s = d = e - E; }
    int pos = atomicAdd(&cursor[d], 1);
    csr[pos] = s;
}

// ============ agg1: one wave per (node, head); head tables XCD-L2 resident ====
// h: HEAD-MAJOR [4][n][64]; es/ed: [4][n]; head = blockIdx%4 -> XCDs {h, h+4}
__global__ __launch_bounds__(256) void agg1(const unsigned short* __restrict__ h,
                                            const int* __restrict__ csr,
                                            const int* __restrict__ offs,
                                            const float* __restrict__ es,
                                            const float* __restrict__ ed,
                                            const float* __restrict__ b1,
                                            unsigned short* __restrict__ outs, int n) {
    const int head = blockIdx.x & 3;
    const int node = (blockIdx.x >> 2) * 4 + (threadIdx.x >> 6);
    const int lane = threadIdx.x & 63;
    if (node >= n) return;
    const unsigned short* ht = h + (size_t)head * n * 64;
    const float* esh = es + (size_t)head * n;
    float edst = ed[(size_t)head * n + node];
    int j0 = offs[node], j1 = offs[node + 1];
    float z0 = 0.f, z1 = 0.f, z2 = 0.f, z3 = 0.f;
    float a0 = 0.f, a1 = 0.f, a2 = 0.f, a3 = 0.f;
    int j = j0;
    for (; j + 4 <= j1; j += 4) {
        int s0 = csr[j], s1 = csr[j + 1], s2 = csr[j + 2], s3 = csr[j + 3];
        unsigned short w0 = ht[(size_t)s0 * 64 + lane];
        unsigned short w1 = ht[(size_t)s1 * 64 + lane];
        unsigned short w2 = ht[(size_t)s2 * 64 + lane];
        unsigned short w3 = ht[(size_t)s3 * 64 + lane];
        float l0 = esh[s0] + edst, l1 = esh[s1] + edst;
        float l2 = esh[s2] + edst, l3 = esh[s3] + edst;
        l0 = (l0 > 0.f) ? l0 : NEG * l0;
        l1 = (l1 > 0.f) ? l1 : NEG * l1;
        l2 = (l2 > 0.f) ? l2 : NEG * l2;
        l3 = (l3 > 0.f) ? l3 : NEG * l3;
        float p0 = __expf(l0), p1 = __expf(l1), p2 = __expf(l2), p3 = __expf(l3);
        z0 += p0; z1 += p1; z2 += p2; z3 += p3;
        a0 = fmaf(p0, bf2f(w0), a0);
        a1 = fmaf(p1, bf2f(w1), a1);
        a2 = fmaf(p2, bf2f(w2), a2);
        a3 = fmaf(p3, bf2f(w3), a3);
    }
    for (; j < j1; ++j) {
        int s0 = csr[j];
        unsigned short w0 = ht[(size_t)s0 * 64 + lane];
        float l0 = esh[s0] + edst;
        l0 = (l0 > 0.f) ? l0 : NEG * l0;
        float p0 = __expf(l0);
        z0 += p0;
        a0 = fmaf(p0, bf2f(w0), a0);
    }
    float z = (z0 + z1) + (z2 + z3);
    float r = ((a0 + a1) + (a2 + a3)) / z + b1[head * 64 + lane];
    r = (r > 0.f) ? r : (__expf(r) - 1.f);  // ELU
    unsigned short qh = f2bf(r);
    // stacked [hi(256)|lo(256)] layout for GEMM2's split-bf16 input
    outs[(size_t)node * 512 + head * 64 + lane] = qh;
    outs[(size_t)node * 512 + 256 + head * 64 + lane] = f2bf(r - bf2f(qh));
}

// ============ agg2 (table 2.5 MB: fits per-XCD L2 as-is) ============
__global__ __launch_bounds__(256) void agg2(const unsigned short* __restrict__ h,
                                            const int* __restrict__ csr,
                                            const int* __restrict__ offs,
                                            const float* __restrict__ es,
                                            const float* __restrict__ ed,
                                            const float* __restrict__ b2,
                                            float* __restrict__ out, int n) {
    int node = blockIdx.x * 4 + (threadIdx.x >> 6);
    int lane = threadIdx.x & 63;
    if (node >= n) return;
    float edst = ed[node];
    int j0 = offs[node], j1 = offs[node + 1];
    float z0 = 0.f, z1 = 0.f, z2 = 0.f, z3 = 0.f;
    float a0 = 0.f, a1 = 0.f, a2 = 0.f, a3 = 0.f;
    int j = j0;
    for (; j + 4 <= j1; j += 4) {
        int s0 = csr[j], s1 = csr[j + 1], s2 = csr[j + 2], s3 = csr[j + 3];
        unsigned short w0 = h[(size_t)s0 * 64 + lane];
        unsigned short w1 = h[(size_t)s1 * 64 + lane];
        unsigned short w2 = h[(size_t)s2 * 64 + lane];
        unsigned short w3 = h[(size_t)s3 * 64 + lane];
        float l0 = es[s0] + edst, l1 = es[s1] + edst, l2 = es[s2] + edst, l3 = es[s3] + edst;
        l0 = (l0 > 0.f) ? l0 : NEG * l0;
        l1 = (l1 > 0.f) ? l1 : NEG * l1;
        l2 = (l2 > 0.f) ? l2 : NEG * l2;
        l3 = (l3 > 0.f) ? l3 : NEG * l3;
        float p0 = __expf(l0), p1 = __expf(l1), p2 = __expf(l2), p3 = __expf(l3);
        z0 += p0; z1 += p1; z2 += p2; z3 += p3;
        a0 = fmaf(p0, bf2f(w0), a0);
        a1 = fmaf(p1, bf2f(w1), a1);
        a2 = fmaf(p2, bf2f(w2), a2);
        a3 = fmaf(p3, bf2f(w3), a3);
    }
    for (; j < j1; ++j) {
        int s0 = csr[j];
        unsigned short w0 = h[(size_t)s0 * 64 + lane];
        float l0 = es[s0] + edst;
        l0 = (l0 > 0.f) ? l0 : NEG * l0;
        float p0 = __expf(l0);
        z0 += p0;
        a0 = fmaf(p0, bf2f(w0), a0);
    }
    float z = (z0 + z1) + (z2 + z3);
    out[(size_t)node * 64 + lane] = ((a0 + a1) + (a2 + a3)) / z + b2[lane];
}

// ============ launch ============
extern "C" void kernel_launch(void* const* d_in, const int* in_sizes, int n_in,
                              void* d_out, int out_size, void* d_ws, size_t ws_size,
                              hipStream_t stream) {
    const float* x   = (const float*)d_in[0];
    const int*   ei  = (const int*)d_in[1];
    const float* W1  = (const float*)d_in[2];
    const float* a1s = (const float*)d_in[3];
    const float* a1d = (const float*)d_in[4];
    const float* b1  = (const float*)d_in[5];
    const float* W2  = (const float*)d_in[6];
    const float* a2s = (const float*)d_in[7];
    const float* a2d = (const float*)d_in[8];
    const float* b2  = (const float*)d_in[9];
    float* out = (float*)d_out;

    const int N = in_sizes[0] / 256;   // 20000
    const int E = in_sizes[1] / 2;     // 320000
    const int EP = E + N;

    char* p = (char*)d_ws;
    auto take = [&](size_t bytes) {
        char* r = p;
        p += (bytes + 255) & ~(size_t)255;
        return r;
    };
    int* deg    = (int*)take((size_t)N * 4);
    int* offs   = (int*)take((size_t)(N + 1) * 4);
    int* cursor = (int*)take((size_t)N * 4);
    int* csr    = (int*)take((size_t)EP * 4);
    unsigned short* hstk = (unsigned short*)take((size_t)N * 512 * 2); // x' then h1a' (aliased, stream-ordered)
    unsigned short* Wt1  = (unsigned short*)take((size_t)256 * 768 * 2);
    unsigned short* Wt2  = (unsigned short*)take((size_t)64 * 768 * 2);
    unsigned short* h1   = (unsigned short*)take((size_t)N * 256 * 2);  // head-major [4][N][64]
    unsigned short* h2   = (unsigned short*)take((size_t)N * 64 * 2);
    float* es1 = (float*)take((size_t)N * 4 * 4);  // head-major [4][N]
    float* ed1 = (float*)take((size_t)N * 4 * 4);
    float* es2 = (float*)take((size_t)N * 4);
    float* ed2 = (float*)take((size_t)N * 4);

    // K1: conv_x + conv_w + zero(deg)
    int xb = (N * 64 + 255) / 256;
    int wb = (256 * 768 + 64 * 768 + 255) / 256;
    int zb = (N + 255) / 256;
    pre<<<xb + wb + zb, 256, 0, stream>>>(x, W1, W2, hstk, Wt1, Wt2, deg, xb, wb, N);

    // K2-K4: CSR
    int eb = (EP + 255) / 256;
    build_deg<<<eb, 256, 0, stream>>>(ei, E, N, deg);
    scan_deg<<<1, 1024, 0, stream>>>(deg, offs, cursor, N);
    fill_csr<<<eb, 256, 0, stream>>>(ei, E, N, cursor, csr);

    // K5: layer-1 GEMM + scores (head-major outputs)
    dim3 g1(2, (N + 127) / 128);
    gemm1_scores<<<g1, 256, 0, stream>>>(hstk, Wt1, h1, a1s, a1d, es1, ed1, N);

    // K6: layer-1 aggregation — one wave per (node, head), XCD-local tables
    int ngrp = (N + 3) / 4;
    agg1<<<ngrp * 4, 256, 0, stream>>>(h1, csr, offs, es1, ed1, b1, hstk, N);

    // K7: layer-2 GEMM + scores
    dim3 g2(1, (N + 127) / 128);
    gemm2_scores<<<g2, 256, 0, stream>>>(hstk, Wt2, h2, a2s, a2d, es2, ed2, N);

    // K8: layer-2 aggregation -> out
    agg2<<<ngrp, 256, 0, stream>>>(h2, csr, offs, es2, ed2, b2, out, N);
}